// Round 5
// baseline (249.428 us; speedup 1.0000x reference)
//
#include <hip/hip_runtime.h>
#include <hip/hip_bf16.h>
#include <math.h>

// ScaledDotProductAttention, masked_softmax semantics (clip ±15, mask-mult,
// exp(x - max), re-mask, /(sum+1e-6)). B=16, L=2048, D=64, TEMP=8.
//
// Round-5: occupancy restructure. Rounds 2-4 proved the single-kernel layout
// is latency-bound at 8 waves/CU (q-parallelism caps total waves at 2048).
// Fixed-shift softmax (M'=15) makes partial exp-sums and partial O additive,
// so split k across blocks:
//   kernel 1: 2048 blocks (4-way k-split), partial exp-sums -> ws, mask
//             packed to 8MB bitmask in ws (kills the 2nd 268MB mask read).
//   kernel 2: 1024 blocks (2-way k-parity split per block), reads sums ->
//             inv, recomputes S, writes attn, PV; partner waves combine O.

typedef __bf16 bf16x8v __attribute__((ext_vector_type(8)));
typedef __bf16 bf16x4v __attribute__((ext_vector_type(4)));
typedef __bf16 bf16x2v __attribute__((ext_vector_type(2)));
typedef float  f32x4   __attribute__((ext_vector_type(4)));
typedef int    i32x4   __attribute__((ext_vector_type(4)));

#define B_  16
#define L_  2048
#define D_  64

// swizzled byte offset within a [rows][64] bf16 tile (128 B per row)
__device__ __forceinline__ int swz(int row, int colb) {
    return (row * 128 + colb) ^ ((row & 7) << 4);
}

// ============================ KERNEL 1: sums ============================
// grid 2048 = [xcd-remap] b(16) x qgroup(32, 64 rows) x ksplit(4, 512 ks)
// Each wave: 16 q-rows x 8 k-tiles. Writes sums[ks][b][q] and bitmask.
template<bool WB>
__global__ __launch_bounds__(256, 6)
void sdpa_sum_kernel(const float* __restrict__ qg,
                     const float* __restrict__ kg,
                     const int*   __restrict__ mg,
                     float* __restrict__ sums,          // [4][B][L]
                     unsigned short* __restrict__ bitm) // [b][q][kc][g] u16
{
    __shared__ __align__(16) char KtB[8192];   // K tile bf16 [64][64] swz

    const int t  = threadIdx.x;
    const int w  = t >> 6;
    const int l  = t & 63;
    const int lq = l & 15;
    const int g  = l >> 4;

    // XCD remap: 2048 blocks -> XCD x gets virt [x*256, x*256+256) = 2 batches
    const int bid  = blockIdx.x;
    const int virt = (bid & 7) * 256 + (bid >> 3);
    const int b    = virt >> 7;
    const int rest = virt & 127;
    const int qgr  = rest >> 2;      // 0..31
    const int ks   = rest & 3;       // 0..3
    const int q0   = qgr * 64;
    const int qi   = q0 + w * 16 + lq;
    const int kc0  = ks * 8;         // first of 8 tiles

    const size_t kvbase = (size_t)b * (L_ * D_);
    const size_t mrow   = ((size_t)b * L_ + qi) * L_;

    // Q fragments (B operand), 1/8 folded in
    bf16x8v qf0, qf1;
    {
        const float* qrow = qg + ((size_t)b * L_ + qi) * D_;
        const f32x4* p0 = (const f32x4*)(qrow + g * 8);
        const f32x4* p1 = (const f32x4*)(qrow + 32 + g * 8);
        f32x4 x0 = p0[0], x1 = p0[1], x2 = p1[0], x3 = p1[1];
        #pragma unroll
        for (int j = 0; j < 4; ++j) {
            qf0[j]     = (__bf16)(x0[j] * 0.125f);
            qf0[4 + j] = (__bf16)(x1[j] * 0.125f);
            qf1[j]     = (__bf16)(x2[j] * 0.125f);
            qf1[4 + j] = (__bf16)(x3[j] * 0.125f);
        }
    }

    const int sr  = t >> 2;
    const int scb = (t & 3) * 32;
    const float* kbase = kg + kvbase + (size_t)(kc0 * 64 + sr) * D_ + (t & 3) * 16;

    float rS0 = 0.f, rS1 = 0.f;
    #pragma unroll 1
    for (int kci = 0; kci < 8; ++kci) {
        __syncthreads();
        {   // stage K tile
            const f32x4* s = (const f32x4*)(kbase + (size_t)kci * (64 * D_));
            f32x4 a = s[0], bb = s[1], c = s[2], d = s[3];
            bf16x8v h0, h1;
            #pragma unroll
            for (int j = 0; j < 4; ++j) {
                h0[j] = (__bf16)a[j]; h0[4 + j] = (__bf16)bb[j];
                h1[j] = (__bf16)c[j]; h1[4 + j] = (__bf16)d[j];
            }
            *(bf16x8v*)(KtB + swz(sr, scb))      = h0;
            *(bf16x8v*)(KtB + swz(sr, scb + 16)) = h1;
        }
        __syncthreads();
        const int kc = kc0 + kci;
        unsigned mbits = 0;
        #pragma unroll
        for (int sub = 0; sub < 4; ++sub) {
            bf16x8v a0 = *(const bf16x8v*)(KtB + swz(sub * 16 + lq, g * 16));
            bf16x8v a1 = *(const bf16x8v*)(KtB + swz(sub * 16 + lq, 64 + g * 16));
            f32x4 s = {0.f, 0.f, 0.f, 0.f};
            s = __builtin_amdgcn_mfma_f32_16x16x32_bf16(a0, qf0, s, 0, 0, 0);
            s = __builtin_amdgcn_mfma_f32_16x16x32_bf16(a1, qf1, s, 0, 0, 0);
            i32x4 mv = *(const i32x4*)(mg + mrow + kc * 64 + sub * 16 + g * 4);
            #pragma unroll
            for (int r = 0; r < 4; ++r) {
                bool mm = (mv[r] != 0);
                mbits |= mm ? (1u << (sub * 4 + r)) : 0u;
                float y = mm ? (fminf(fmaxf(s[r], -15.f), 15.f) - 15.f) : -1e30f;
                if (r & 1) rS1 += __expf(y); else rS0 += __expf(y);
            }
        }
        if (WB) bitm[(size_t)(b * L_ + qi) * 128 + kc * 4 + g] = (unsigned short)mbits;
    }
    float rS = rS0 + rS1;
    rS += __shfl_xor(rS, 16, 64);
    rS += __shfl_xor(rS, 32, 64);
    if (l < 16) sums[((size_t)ks * B_ + b) * L_ + qi] = rS;
}

// ============================ KERNEL 2: output ============================
// grid 1024 = [xcd-remap] b(16) x qgroup(64, 32 rows). Waves 0,1: rows 0-15
// (even/odd tiles); waves 2,3: rows 16-31. Partial O combined via LDS.
template<bool UB>
__global__ __launch_bounds__(256, 4)
void sdpa_out_kernel(const float* __restrict__ qg,
                     const float* __restrict__ kg,
                     const float* __restrict__ vg,
                     const int*   __restrict__ mg,
                     const float* __restrict__ sums,
                     const unsigned short* __restrict__ bitm,
                     float* __restrict__ outg,    // [B][L][D]
                     float* __restrict__ attng)   // [B][L][L]
{
    __shared__ __align__(16) char KtB[2][8192];   // K tiles (pair) swz
    __shared__ __align__(16) char VtB[2][8192];   // V^T tiles (pair) swz
    __shared__ __align__(16) char PwB[4][2048];   // per-wave P swz

    const int t  = threadIdx.x;
    const int w  = t >> 6;
    const int l  = t & 63;
    const int lq = l & 15;
    const int g  = l >> 4;
    const int par = w & 1;         // tile parity this wave computes
    const int qh  = w >> 1;        // q-half within block

    // XCD remap: 1024 blocks -> XCD x gets 2 batches
    const int bid  = blockIdx.x;
    const int virt = (bid & 7) * 128 + (bid >> 3);
    const int b    = virt >> 6;
    const int qgr  = virt & 63;
    const int q0   = qgr * 32;
    const int qi   = q0 + qh * 16 + lq;

    const size_t kvbase = (size_t)b * (L_ * D_);
    const size_t mrow   = ((size_t)b * L_ + qi) * L_;

    // inv from the 4 k-split partial sums
    float s4 = sums[((size_t)0 * B_ + b) * L_ + qi]
             + sums[((size_t)1 * B_ + b) * L_ + qi]
             + sums[((size_t)2 * B_ + b) * L_ + qi]
             + sums[((size_t)3 * B_ + b) * L_ + qi];
    const float inv = 1.f / (s4 + 1e-6f);

    // Q fragments
    bf16x8v qf0, qf1;
    {
        const float* qrow = qg + ((size_t)b * L_ + qi) * D_;
        const f32x4* p0 = (const f32x4*)(qrow + g * 8);
        const f32x4* p1 = (const f32x4*)(qrow + 32 + g * 8);
        f32x4 x0 = p0[0], x1 = p0[1], x2 = p1[0], x3 = p1[1];
        #pragma unroll
        for (int j = 0; j < 4; ++j) {
            qf0[j]     = (__bf16)(x0[j] * 0.125f);
            qf0[4 + j] = (__bf16)(x1[j] * 0.125f);
            qf1[j]     = (__bf16)(x2[j] * 0.125f);
            qf1[4 + j] = (__bf16)(x3[j] * 0.125f);
        }
    }

    // staging geometry
    const int sr  = t >> 2;
    const int scb = (t & 3) * 32;
    const float* kbase  = kg + kvbase + (size_t)sr * D_ + (t & 3) * 16;
    const int kp = t & 31, dg = t >> 5;
    const float* vbase0 = vg + kvbase + (size_t)(2 * kp) * D_ + dg * 8;

    auto stageK = [&](int kc, char* buf) {
        const f32x4* s = (const f32x4*)(kbase + (size_t)kc * (64 * D_));
        f32x4 a = s[0], bb = s[1], c = s[2], d = s[3];
        bf16x8v h0, h1;
        #pragma unroll
        for (int j = 0; j < 4; ++j) {
            h0[j] = (__bf16)a[j]; h0[4 + j] = (__bf16)bb[j];
            h1[j] = (__bf16)c[j]; h1[4 + j] = (__bf16)d[j];
        }
        *(bf16x8v*)(buf + swz(sr, scb))      = h0;
        *(bf16x8v*)(buf + swz(sr, scb + 16)) = h1;
    };
    auto stageV = [&](int kc, char* buf) {
        const float* r0 = vbase0 + (size_t)kc * (64 * D_);
        const f32x4* s0 = (const f32x4*)r0;
        const f32x4* s1 = (const f32x4*)(r0 + D_);
        f32x4 a = s0[0], bb = s0[1], c = s1[0], d = s1[1];
        #pragma unroll
        for (int j = 0; j < 4; ++j) {
            bf16x2v p0; p0[0] = (__bf16)a[j];  p0[1] = (__bf16)c[j];
            *(bf16x2v*)(buf + swz(dg * 8 + j, kp * 4)) = p0;
            bf16x2v p1; p1[0] = (__bf16)bb[j]; p1[1] = (__bf16)d[j];
            *(bf16x2v*)(buf + swz(dg * 8 + 4 + j, kp * 4)) = p1;
        }
    };

    f32x4 acc[4];
    #pragma unroll
    for (int i = 0; i < 4; ++i) acc[i] = (f32x4){0.f, 0.f, 0.f, 0.f};

    #pragma unroll 1
    for (int tp = 0; tp < 16; ++tp) {
        __syncthreads();
        stageK(2 * tp,     KtB[0]);
        stageK(2 * tp + 1, KtB[1]);
        stageV(2 * tp,     VtB[0]);
        stageV(2 * tp + 1, VtB[1]);
        __syncthreads();

        const int kc = 2 * tp + par;
        const char* KB = KtB[par];
        const char* VB = VtB[par];
        unsigned mbits = 0;
        if (UB) mbits = bitm[(size_t)(b * L_ + qi) * 128 + kc * 4 + g];

        #pragma unroll
        for (int sub = 0; sub < 4; ++sub) {
            bf16x8v a0 = *(const bf16x8v*)(KB + swz(sub * 16 + lq, g * 16));
            bf16x8v a1 = *(const bf16x8v*)(KB + swz(sub * 16 + lq, 64 + g * 16));
            f32x4 s = {0.f, 0.f, 0.f, 0.f};
            s = __builtin_amdgcn_mfma_f32_16x16x32_bf16(a0, qf0, s, 0, 0, 0);
            s = __builtin_amdgcn_mfma_f32_16x16x32_bf16(a1, qf1, s, 0, 0, 0);
            i32x4 mv;
            if (!UB) mv = *(const i32x4*)(mg + mrow + kc * 64 + sub * 16 + g * 4);
            f32x4 pv; bf16x4v pb;
            #pragma unroll
            for (int r = 0; r < 4; ++r) {
                bool mm = UB ? (((mbits >> (sub * 4 + r)) & 1u) != 0u) : (mv[r] != 0);
                float y = mm ? (fminf(fmaxf(s[r], -15.f), 15.f) - 15.f) : -1e30f;
                float p = __expf(y) * inv;
                pv[r] = p; pb[r] = (__bf16)p;
            }
            *(f32x4*)(attng + mrow + kc * 64 + sub * 16 + g * 4) = pv;
            *(bf16x4v*)(PwB[w] + swz(lq, (sub * 16 + g * 4) * 2)) = pb;
        }
        #pragma unroll
        for (int kss = 0; kss < 2; ++kss) {
            bf16x8v pa = *(const bf16x8v*)(PwB[w] + swz(lq, kss * 64 + g * 16));
            #pragma unroll
            for (int dt = 0; dt < 4; ++dt) {
                bf16x8v vb = *(const bf16x8v*)(VB + swz(dt * 16 + lq, kss * 64 + g * 16));
                acc[dt] = __builtin_amdgcn_mfma_f32_16x16x32_bf16(pa, vb, acc[dt], 0, 0, 0);
            }
        }
    }

    // combine partial O across parity partners (reuse KtB as [2][16][68] f32)
    __syncthreads();
    float* POut = (float*)&KtB[0][0];
    if (par == 1) {
        #pragma unroll
        for (int dt = 0; dt < 4; ++dt)
            #pragma unroll
            for (int r = 0; r < 4; ++r)
                POut[qh * 1088 + (g * 4 + r) * 68 + dt * 16 + lq] = acc[dt][r];
    }
    __syncthreads();
    if (par == 0) {
        #pragma unroll
        for (int dt = 0; dt < 4; ++dt)
            #pragma unroll
            for (int r = 0; r < 4; ++r) {
                float o = acc[dt][r] + POut[qh * 1088 + (g * 4 + r) * 68 + dt * 16 + lq];
                outg[((size_t)b * L_ + (q0 + qh * 16 + g * 4 + r)) * D_ + dt * 16 + lq] = o;
            }
    }
}

extern "C" void kernel_launch(void* const* d_in, const int* in_sizes, int n_in,
                              void* d_out, int out_size, void* d_ws, size_t ws_size,
                              hipStream_t stream) {
    (void)in_sizes; (void)n_in; (void)out_size;
    const float* q = (const float*)d_in[0];
    const float* k = (const float*)d_in[1];
    const float* v = (const float*)d_in[2];
    const int*   m = (const int*)d_in[3];
    float* out  = (float*)d_out;
    float* attn = out + (size_t)B_ * L_ * D_;

    float* sums = (float*)d_ws;                                   // 512 KB
    unsigned short* bitm = (unsigned short*)((char*)d_ws + 524288); // 8 MB
    const size_t need = 524288 + (size_t)B_ * L_ * 128 * 2;

    dim3 blk(256);
    if (ws_size >= need) {
        hipLaunchKernelGGL((sdpa_sum_kernel<true>),  dim3(2048), blk, 0, stream,
                           q, k, m, sums, bitm);
        hipLaunchKernelGGL((sdpa_out_kernel<true>),  dim3(1024), blk, 0, stream,
                           q, k, v, m, sums, bitm, out, attn);
    } else {
        hipLaunchKernelGGL((sdpa_sum_kernel<false>), dim3(2048), blk, 0, stream,
                           q, k, m, sums, nullptr);
        hipLaunchKernelGGL((sdpa_out_kernel<false>), dim3(1024), blk, 0, stream,
                           q, k, v, m, sums, nullptr, out, attn);
    }
}